// Round 15
// baseline (159.743 us; speedup 1.0000x reference)
//
#include <hip/hip_runtime.h>
#include <hip/hip_bf16.h>

#define NN 512
#define NH 64
#define MAXD 96            // list capacity (deg mean 32, sigma 5.5 -> +11 sigma)
#define ZBYTE (511 * 128)  // sentinel -> byte offset of row 511 (deg=0 zeroes it)
#define REP_BG 8           // DIAGNOSTIC: internal repeat of build_gemms body

typedef _Float16 h4 __attribute__((ext_vector_type(4)));

// ---------------- ws layout (bytes) ----------------
// nbr   : NN*MAXD*4 = 196608  @ 0        entries = r*128 (byte row offset), sentinel ZBYTE
// g16   : NN*NH*2   = 65536   @ 196608   fp16 z@W1 tile (unscaled)
// pcntC : NN*NN     = 262144  @ 262144   u8 pcntC[c][t]
// pcntT : NN*NN     = 262144  @ 524288   u8 pcntT[i][c]
// ph    : NN*NN*4   = 1048576 @ 786432   f32 ph[i][k] = deg_k*hid[i][k], valid k<i
// st    : NN*NN*4   = 1048576 @ 1835008  f32 half-supplement, zero for j>=i
// total = 2883584

__global__ __launch_bounds__(512) void build_gemms(const float* __restrict__ adj,
                                                   const float* __restrict__ z,
                                                   const float* __restrict__ W1,
                                                   unsigned* __restrict__ nbr,
                                                   unsigned char* __restrict__ pcntC,
                                                   _Float16* __restrict__ g16,
                                                   float* __restrict__ out) {
    __shared__ float As[32][68];
    __shared__ float Bs[32][68];
    __shared__ int wcnt[8];
    const int b = (int)blockIdx.x;
    const int tid = (int)threadIdx.x;
    const int lane = tid & 63, w = tid >> 6;

    for (int rep = 0; rep < REP_BG; ++rep) {   // DIAGNOSTIC repeat (idempotent)
        {   // build lists + own pcntC row for column c = b (adj symmetric)
            const int c = b;
            bool f = (adj[c * NN + tid] != 0.0f);
            unsigned long long m = __ballot(f);
            int before = __popcll(m & ((1ull << lane) - 1ull));
            if (lane == 0) wcnt[w] = __popcll(m);
            __syncthreads();
            int pre = 0, total = 0;
            #pragma unroll
            for (int j = 0; j < 8; ++j) {
                int x = wcnt[j];
                pre += (j < w) ? x : 0;
                total += x;
            }
            pcntC[c * NN + tid] = (unsigned char)(pre + before);
            unsigned* row = nbr + c * MAXD;
            int pos = pre + before;
            if (f && pos < MAXD) row[pos] = (unsigned)(tid << 7);
            int m2 = total < MAXD ? total : MAXD;
            for (int j = m2 + tid; j < MAXD; j += 512) row[j] = ZBYTE;
            __syncthreads();
        }

        const int tx = tid & 15, ty = tid >> 4;   // 16 x 32 thread grid
        if (b < 64) {
            const int bi = b >> 3, bj = b & 7;
            float acc[2][4] = {};
            for (int kk = 0; kk < 256; kk += 32) {
                #pragma unroll
                for (int l = 0; l < 4; ++l) {
                    int id = tid + (l << 9);
                    int m = id >> 5, k = id & 31;
                    As[k][m] = z[(bi * 64 + m) * 256 + kk + k];
                    Bs[k][m] = z[(bj * 64 + m) * 256 + kk + k];
                }
                __syncthreads();
                #pragma unroll
                for (int k = 0; k < 32; ++k) {
                    float2 a = *(const float2*)&As[k][ty * 2];
                    float4 bb = *(const float4*)&Bs[k][tx * 4];
                    float ar[2] = {a.x, a.y};
                    float br[4] = {bb.x, bb.y, bb.z, bb.w};
                    #pragma unroll
                    for (int p = 0; p < 2; ++p)
                        #pragma unroll
                        for (int q = 0; q < 4; ++q)
                            acc[p][q] = fmaf(ar[p], br[q], acc[p][q]);
                }
                __syncthreads();
            }
            #pragma unroll
            for (int p = 0; p < 2; ++p) {
                float4 stv = make_float4(acc[p][0], acc[p][1], acc[p][2], acc[p][3]);
                *(float4*)&out[(bi * 64 + ty * 2 + p) * NN + bj * 64 + tx * 4] = stv;
            }
        } else if (b < 72) {
            const int bi = b - 64;
            float acc[2][4] = {};
            for (int kk = 0; kk < 256; kk += 32) {
                #pragma unroll
                for (int l = 0; l < 4; ++l) {
                    int id = tid + (l << 9);
                    int m = id >> 5, k = id & 31;
                    As[k][m] = z[(bi * 64 + m) * 256 + kk + k];
                }
                #pragma unroll
                for (int l = 0; l < 4; ++l) {
                    int id = tid + (l << 9);
                    int k = id >> 6, n2 = id & 63;
                    Bs[k][n2] = W1[(kk + k) * 64 + n2];
                }
                __syncthreads();
                #pragma unroll
                for (int k = 0; k < 32; ++k) {
                    float2 a = *(const float2*)&As[k][ty * 2];
                    float4 bb = *(const float4*)&Bs[k][tx * 4];
                    float ar[2] = {a.x, a.y};
                    float br[4] = {bb.x, bb.y, bb.z, bb.w};
                    #pragma unroll
                    for (int p = 0; p < 2; ++p)
                        #pragma unroll
                        for (int q = 0; q < 4; ++q)
                            acc[p][q] = fmaf(ar[p], br[q], acc[p][q]);
                }
                __syncthreads();
            }
            #pragma unroll
            for (int p = 0; p < 2; ++p) {
                h4 v = {(_Float16)acc[p][0], (_Float16)acc[p][1],
                        (_Float16)acc[p][2], (_Float16)acc[p][3]};
                *(h4*)&g16[(bi * 64 + ty * 2 + p) * NH + tx * 4] = v;
            }
        }
        __syncthreads();
    }
}

// K1b: byte transpose pcntT[t][c] = pcntC[c][t].
__global__ __launch_bounds__(512) void transp(const unsigned char* __restrict__ pcntC,
                                              unsigned char* __restrict__ pcntT) {
    __shared__ unsigned char til[64][72];
    const int bx = (int)blockIdx.x;
    const int br = bx >> 3, bc = bx & 7;
    const int tid = (int)threadIdx.x;
    const int rr = tid >> 3, c8 = (tid & 7) << 3;
    unsigned long long v = *(const unsigned long long*)
        &pcntC[(bc * 64 + rr) * NN + br * 64 + c8];
    #pragma unroll
    for (int u = 0; u < 8; ++u) til[rr][c8 + u] = (unsigned char)(v >> (u * 8));
    __syncthreads();
    unsigned long long o = 0;
    #pragma unroll
    for (int u = 0; u < 8; ++u)
        o |= (unsigned long long)til[c8 + u][rr] << (u * 8);
    *(unsigned long long*)&pcntT[(br * 64 + rr) * NN + bc * 64 + c8] = o;
}

// K2: visit-balanced hid (launched 3x this round: idempotent; increment
// measures 2*t_hidk + 2*boundary).
__global__ __launch_bounds__(1024, 8) void hidk(const unsigned* __restrict__ nbr,
                                                const unsigned char* __restrict__ pcntT,
                                                const _Float16* __restrict__ g16,
                                                const float* __restrict__ W2,
                                                float* __restrict__ ph) {
    __shared__ _Float16 g2[NN * NH];   // 64 KB deg-scaled tile
    __shared__ float degl[NN];
    __shared__ unsigned char pcl[NN];
    const int i = 511 - (int)blockIdx.y;
    const int c = (int)blockIdx.x;
    const int kc0 = (c * i) / 3, kc1 = ((c + 1) * i) / 3;
    if (kc0 >= kc1) return;
    const int tid = threadIdx.x, lane = tid & 63, w = tid >> 6;

    if (tid < NN) {
        int pc = (int)pcntT[i * NN + tid];
        pcl[tid] = (unsigned char)pc;
        degl[tid] = (tid < i) ? rsqrtf((float)(pc > 0 ? pc : 1)) : 0.0f;
    }
    __syncthreads();
    {
        const uint4* s = (const uint4*)g16;
        uint4* d = (uint4*)g2;
        #pragma unroll
        for (int u = 0; u < 4; ++u) {
            int t = tid + (u << 10);
            int l = t >> 3;
            uint4 raw = s[t];
            _Float16 dh = (_Float16)degl[l];
            h4 dv = {dh, dh, dh, dh};
            h4 a0 = ((h4*)&raw)[0] * dv;
            h4 a1 = ((h4*)&raw)[1] * dv;
            uint4 o;
            ((h4*)&o)[0] = a0; ((h4*)&o)[1] = a1;
            d[t] = o;
        }
    }
    __syncthreads();

    const int q = lane >> 4;
    const int lofs = (lane & 15) << 3;
    const float4 w2v = *(const float4*)&W2[(lane & 15) << 2];
    const char* g2b = (const char*)g2;

    for (int k0 = kc0 + (w << 2); k0 < kc1; k0 += 64) {
        const int kq = k0 + q;
        const int kqc = kq < 511 ? kq : 511;
        int pk = (kq < kc1) ? (int)pcl[kqc] : 0;
        int mx = max(pk, __shfl_xor(pk, 16, 64));
        mx = max(mx, __shfl_xor(mx, 32, 64));
        const int nbu = __builtin_amdgcn_readfirstlane((mx + 3) >> 2);
        const uint4* l4 = (const uint4*)(nbr + kqc * MAXD);
        h4 acc0 = {}, acc1 = {};
        uint4 e0 = l4[0], e1 = l4[1];
        for (int g = 0; g < nbu; ++g) {
            uint4 en = l4[g + 2];
            acc0 += *(const h4*)(g2b + (e0.x + lofs));
            acc1 += *(const h4*)(g2b + (e0.y + lofs));
            acc0 += *(const h4*)(g2b + (e0.z + lofs));
            acc1 += *(const h4*)(g2b + (e0.w + lofs));
            e0 = e1; e1 = en;
        }
        h4 acc = acc0 + acc1;
        const float dk = degl[kqc];
        float val = fmaxf(dk * (float)acc[0], 0.f) * w2v.x
                  + fmaxf(dk * (float)acc[1], 0.f) * w2v.y
                  + fmaxf(dk * (float)acc[2], 0.f) * w2v.z
                  + fmaxf(dk * (float)acc[3], 0.f) * w2v.w;
        #pragma unroll
        for (int mm = 1; mm <= 8; mm <<= 1) val += __shfl_xor(val, mm, 64);
        if ((lane & 15) == 0 && kq < kc1) ph[i * NN + kq] = dk * val;
    }
}

// K3: half-supplement, row store only (REP removed).
__global__ __launch_bounds__(512) void supp(const unsigned* __restrict__ nbr,
                                            const unsigned char* __restrict__ pcntT,
                                            const float* __restrict__ ph,
                                            float* __restrict__ st) {
    __shared__ float phl[NN];
    const int i = 511 - (int)blockIdx.x;
    const int tid = threadIdx.x;
    const int pc = (int)pcntT[i * NN + tid];
    phl[tid] = (tid < i) ? ph[i * NN + tid] : 0.0f;
    __syncthreads();
    float sj = 0.0f;
    if (tid < i) {
        const float d = rsqrtf((float)(pc > 0 ? pc : 1));
        const uint4* l4 = (const uint4*)(nbr + tid * MAXD);
        const int nb = (pc + 3) >> 2;
        float s = 0.f;
        for (int g = 0; g < nb; ++g) {
            uint4 qv = l4[g];
            s += phl[qv.x >> 7] + phl[qv.y >> 7] + phl[qv.z >> 7] + phl[qv.w >> 7];
        }
        sj = 0.5f * d * s;
    }
    st[i * NN + tid] = sj;
}

// K4: out += st + st^T.
__global__ __launch_bounds__(512) void symm(const float* __restrict__ st,
                                            float* __restrict__ out) {
    __shared__ float tB[64][65];
    const int bx = (int)blockIdx.x;
    const int bi = bx >> 3, bj = bx & 7;
    const int tid = (int)threadIdx.x;
    const int r = tid >> 3, c0 = (tid & 7) << 3;
    float4 b0 = *(const float4*)&st[(bj * 64 + r) * NN + bi * 64 + c0];
    float4 b1 = *(const float4*)&st[(bj * 64 + r) * NN + bi * 64 + c0 + 4];
    *(float4*)&tB[r][c0] = b0;
    *(float4*)&tB[r][c0 + 4] = b1;
    __syncthreads();
    const int o = (bi * 64 + r) * NN + bj * 64 + c0;
    float4 a0 = *(const float4*)&st[o];
    float4 a1 = *(const float4*)&st[o + 4];
    float4 o0 = *(const float4*)&out[o];
    float4 o1 = *(const float4*)&out[o + 4];
    float va[8] = {a0.x, a0.y, a0.z, a0.w, a1.x, a1.y, a1.z, a1.w};
    float vo[8] = {o0.x, o0.y, o0.z, o0.w, o1.x, o1.y, o1.z, o1.w};
    #pragma unroll
    for (int u = 0; u < 8; ++u) vo[u] += va[u] + tB[c0 + u][r];
    *(float4*)&out[o]     = make_float4(vo[0], vo[1], vo[2], vo[3]);
    *(float4*)&out[o + 4] = make_float4(vo[4], vo[5], vo[6], vo[7]);
}

extern "C" void kernel_launch(void* const* d_in, const int* in_sizes, int n_in,
                              void* d_out, int out_size, void* d_ws, size_t ws_size,
                              hipStream_t stream) {
    const float* z   = (const float*)d_in[0];
    const float* adj = (const float*)d_in[1];
    const float* W1  = (const float*)d_in[2];
    const float* W2  = (const float*)d_in[3];
    float* out = (float*)d_out;

    char* wsp = (char*)d_ws;
    unsigned*       nbr   = (unsigned*)      (wsp + 0);
    _Float16*       g16   = (_Float16*)      (wsp + 196608);
    unsigned char*  pcntC = (unsigned char*) (wsp + 262144);
    unsigned char*  pcntT = (unsigned char*) (wsp + 524288);
    float*          ph    = (float*)         (wsp + 786432);
    float*          st    = (float*)         (wsp + 1835008);

    build_gemms<<<NN, 512, 0, stream>>>(adj, z, W1, nbr, pcntC, g16, out);
    transp<<<64, 512, 0, stream>>>(pcntC, pcntT);
    hidk<<<dim3(3, NN), 1024, 0, stream>>>(nbr, pcntT, g16, W2, ph);   // 1
    hidk<<<dim3(3, NN), 1024, 0, stream>>>(nbr, pcntT, g16, W2, ph);   // 2 (diag)
    hidk<<<dim3(3, NN), 1024, 0, stream>>>(nbr, pcntT, g16, W2, ph);   // 3 (diag)
    supp<<<NN, 512, 0, stream>>>(nbr, pcntT, ph, st);
    symm<<<64, 512, 0, stream>>>(st, out);
}

// Round 16
// 84.972 us; speedup vs baseline: 1.8799x; 1.8799x over previous
//
#include <hip/hip_runtime.h>
#include <hip/hip_bf16.h>

#define NN 512
#define NH 64
#define MAXD 96            // list capacity (deg mean 32, sigma 5.5 -> +11 sigma)
#define ZBYTE (511 * 128)  // sentinel -> byte row offset of row 511 (never < i*128)

typedef _Float16 h4 __attribute__((ext_vector_type(4)));

// ---------------- ws layout (bytes) ----------------
// nbr : NN*MAXD*4 = 196608 @ 0       entries = r*128 (byte row offset), sentinel ZBYTE
// g16 : NN*NH*2   = 65536  @ 196608  fp16 z@W1 tile (unscaled)
// ph  : NN*NN*4   = 1048576@ 262144  f32 ph[i][k] = deg_k*hid[i][k], valid k<i
// total = 1310720

// K1: 512 blocks x 512 thr. Every block builds the neighbor list for column
// c = b (adj symmetric -> coalesced row read; ballot compaction preserves
// sorted order). Blocks 0..255 also compute a 32x32 tile of out = z@z^T;
// blocks 256..271 a 32-row slab of g16 = fp16(z @ W1[:256]).
__global__ __launch_bounds__(512) void build_gemms(const float* __restrict__ adj,
                                                   const float* __restrict__ z,
                                                   const float* __restrict__ W1,
                                                   unsigned* __restrict__ nbr,
                                                   _Float16* __restrict__ g16,
                                                   float* __restrict__ out) {
    __shared__ float As[32][34];
    __shared__ float Bs[32][34];
    __shared__ int wcnt[8];
    const int b = (int)blockIdx.x;
    const int tid = (int)threadIdx.x;
    const int lane = tid & 63, w = tid >> 6;

    {   // build list for column c = b
        const int c = b;
        bool f = (adj[c * NN + tid] != 0.0f);
        unsigned long long m = __ballot(f);
        int before = __popcll(m & ((1ull << lane) - 1ull));
        if (lane == 0) wcnt[w] = __popcll(m);
        __syncthreads();
        int pre = 0, total = 0;
        #pragma unroll
        for (int j = 0; j < 8; ++j) {
            int x = wcnt[j];
            pre += (j < w) ? x : 0;
            total += x;
        }
        unsigned* row = nbr + c * MAXD;
        int pos = pre + before;
        if (f && pos < MAXD) row[pos] = (unsigned)(tid << 7);
        int m2 = total < MAXD ? total : MAXD;
        for (int j = m2 + tid; j < MAXD; j += 512) row[j] = ZBYTE;
        __syncthreads();
    }

    const int tx = tid & 15, py = tid >> 4;   // 16 x 32 thread layout
    if (b < 256) {
        // out = z @ z^T, 32x32 tile (bi, bj); 2 outputs/thread
        const int bi = b >> 4, bj = b & 15;
        float acc0 = 0.f, acc1 = 0.f;
        for (int kk = 0; kk < 256; kk += 32) {
            #pragma unroll
            for (int l = 0; l < 2; ++l) {
                int id = tid + (l << 9);
                int m = id >> 5, k = id & 31;
                As[k][m] = z[(bi * 32 + m) * 256 + kk + k];
                Bs[k][m] = z[(bj * 32 + m) * 256 + kk + k];
            }
            __syncthreads();
            #pragma unroll
            for (int k = 0; k < 32; ++k) {
                float a = As[k][py];
                float2 bb = *(const float2*)&Bs[k][tx * 2];
                acc0 = fmaf(a, bb.x, acc0);
                acc1 = fmaf(a, bb.y, acc1);
            }
            __syncthreads();
        }
        *(float2*)&out[(bi * 32 + py) * NN + bj * 32 + tx * 2] = make_float2(acc0, acc1);
    } else if (b < 272) {
        // g16 = fp16(z @ W1[:256]), 32-row slab; 4 outputs/thread
        const int bi = b - 256;
        float (*As2)[34] = As;
        float (*Bs2)[68] = (float(*)[68])&Bs[0][0];   // 16*68 = 1088 floats == Bs
        float a0 = 0.f, a1 = 0.f, a2 = 0.f, a3 = 0.f;
        for (int kk = 0; kk < 256; kk += 16) {
            {
                int m = tid >> 4, k = tid & 15;       // 32 x 16
                As2[k][m] = z[(bi * 32 + m) * 256 + kk + k];
            }
            #pragma unroll
            for (int l = 0; l < 2; ++l) {
                int id = tid + (l << 9);
                int k = id >> 6, n2 = id & 63;        // 16 x 64
                Bs2[k][n2] = W1[(kk + k) * 64 + n2];
            }
            __syncthreads();
            #pragma unroll
            for (int k = 0; k < 16; ++k) {
                float a = As2[k][py];
                float4 bb = *(const float4*)&Bs2[k][tx * 4];
                a0 = fmaf(a, bb.x, a0);
                a1 = fmaf(a, bb.y, a1);
                a2 = fmaf(a, bb.z, a2);
                a3 = fmaf(a, bb.w, a3);
            }
            __syncthreads();
        }
        h4 v = {(_Float16)a0, (_Float16)a1, (_Float16)a2, (_Float16)a3};
        *(h4*)&g16[(bi * 32 + py) * NH + tx * 4] = v;
    }
}

// K2: visit-balanced hid. Grid (3, 512): block (c, b) handles i = 511-b,
// k in [c*i/3, (c+1)*i/3). deg computed INLINE: thread t counts entries of
// list t below i*128 (branchless over padded list; sentinel never counts).
// g2[l][h] = deg_i[l]*g16[l][h], rows >= i zeroed (deg=0) without reading g16.
// Quarter q of each wave owns one k; 2-deep rolling list prefetch.
__global__ __launch_bounds__(1024, 8) void hidk(const unsigned* __restrict__ nbr,
                                                const _Float16* __restrict__ g16,
                                                const float* __restrict__ W2,
                                                float* __restrict__ ph) {
    __shared__ _Float16 g2[NN * NH];   // 64 KB deg-scaled tile
    __shared__ float degl[NN];
    __shared__ short pcl[NN];
    const int i = 511 - (int)blockIdx.y;   // big i first
    const int c = (int)blockIdx.x;
    const int kc0 = (c * i) / 3, kc1 = ((c + 1) * i) / 3;
    if (kc0 >= kc1) return;
    const int tid = threadIdx.x, lane = tid & 63, w = tid >> 6;

    if (tid < NN) {
        const uint4* lst = (const uint4*)(nbr + tid * MAXD);
        const unsigned lim = (unsigned)(i << 7);
        int p = 0;
        #pragma unroll
        for (int u = 0; u < MAXD / 4; ++u) {
            uint4 qv = lst[u];
            p += (qv.x < lim) + (qv.y < lim) + (qv.z < lim) + (qv.w < lim);
        }
        pcl[tid] = (short)p;
        degl[tid] = (tid < i) ? rsqrtf((float)(p > 0 ? p : 1)) : 0.0f;
    }
    __syncthreads();
    {   // stage rows < i scaled; zero rows >= i (no global read)
        const uint4* s = (const uint4*)g16;
        uint4* d = (uint4*)g2;
        const int ci = i << 3;             // uint4 count of live rows
        for (int t = tid; t < ci; t += 1024) {
            int l = t >> 3;
            uint4 raw = s[t];
            _Float16 dh = (_Float16)degl[l];
            h4 dv = {dh, dh, dh, dh};
            h4 a0 = ((h4*)&raw)[0] * dv;
            h4 a1 = ((h4*)&raw)[1] * dv;
            uint4 o;
            ((h4*)&o)[0] = a0; ((h4*)&o)[1] = a1;
            d[t] = o;
        }
        const uint4 zz = {0u, 0u, 0u, 0u};
        for (int t = ci + tid; t < NN * 8; t += 1024) d[t] = zz;
    }
    __syncthreads();

    const int q = lane >> 4;                 // quarter 0..3
    const int lofs = (lane & 15) << 3;       // byte offset within 128B row
    const float4 w2v = *(const float4*)&W2[(lane & 15) << 2];
    const char* g2b = (const char*)g2;

    for (int k0 = kc0 + (w << 2); k0 < kc1; k0 += 64) {
        const int kq = k0 + q;
        const int kqc = kq < 511 ? kq : 511;
        int pk = (kq < kc1) ? (int)pcl[kqc] : 0;
        int mx = max(pk, __shfl_xor(pk, 16, 64));
        mx = max(mx, __shfl_xor(mx, 32, 64));
        const int nbu = __builtin_amdgcn_readfirstlane((mx + 3) >> 2);
        const uint4* l4 = (const uint4*)(nbr + kqc * MAXD);
        h4 acc0 = {}, acc1 = {};
        uint4 e0 = l4[0], e1 = l4[1];        // 2-deep rolling prefetch
        for (int g = 0; g < nbu; ++g) {
            uint4 en = l4[g + 2];            // harmless in-row over-read
            acc0 += *(const h4*)(g2b + (e0.x + lofs));
            acc1 += *(const h4*)(g2b + (e0.y + lofs));
            acc0 += *(const h4*)(g2b + (e0.z + lofs));
            acc1 += *(const h4*)(g2b + (e0.w + lofs));
            e0 = e1; e1 = en;
        }
        h4 acc = acc0 + acc1;
        const float dk = degl[kqc];
        float val = fmaxf(dk * (float)acc[0], 0.f) * w2v.x
                  + fmaxf(dk * (float)acc[1], 0.f) * w2v.y
                  + fmaxf(dk * (float)acc[2], 0.f) * w2v.z
                  + fmaxf(dk * (float)acc[3], 0.f) * w2v.w;
        #pragma unroll
        for (int mm = 1; mm <= 8; mm <<= 1) val += __shfl_xor(val, mm, 64);
        if ((lane & 15) == 0 && kq < kc1) ph[i * NN + kq] = dk * val;  // deg_k*hid
    }
}

// K3: supplement scatter. s[i][j] = 0.5*deg_j*sum_{k in nbr(j), k<i} ph[i][k];
// out[i][j] += s, out[j][i] += s (block i owns row i & col i -> race-free).
// deg_j/pc computed inline like K2. Over-reads hit phl[r>=i] == 0.
__global__ __launch_bounds__(512) void supp(const unsigned* __restrict__ nbr,
                                            const float* __restrict__ ph,
                                            float* __restrict__ out) {
    __shared__ float phl[NN];
    const int i = 511 - (int)blockIdx.x;
    if (i < 1) return;
    const int tid = threadIdx.x;
    const uint4* lst = (const uint4*)(nbr + tid * MAXD);
    const unsigned lim = (unsigned)(i << 7);
    int pc = 0;
    #pragma unroll
    for (int u = 0; u < MAXD / 4; ++u) {
        uint4 qv = lst[u];
        pc += (qv.x < lim) + (qv.y < lim) + (qv.z < lim) + (qv.w < lim);
    }
    phl[tid] = (tid < i) ? ph[i * NN + tid] : 0.0f;   // ph already deg_k-scaled
    __syncthreads();
    if (tid < i) {
        const float d = rsqrtf((float)(pc > 0 ? pc : 1));
        const int nb = (pc + 3) >> 2;
        float s = 0.f;
        for (int g = 0; g < nb; ++g) {
            uint4 qv = lst[g];   // over-read entries land on phl[r>=i] == 0
            s += phl[qv.x >> 7] + phl[qv.y >> 7] + phl[qv.z >> 7] + phl[qv.w >> 7];
        }
        s *= 0.5f * d;
        out[i * NN + tid] += s;
        out[tid * NN + i] += s;
    }
}

extern "C" void kernel_launch(void* const* d_in, const int* in_sizes, int n_in,
                              void* d_out, int out_size, void* d_ws, size_t ws_size,
                              hipStream_t stream) {
    const float* z   = (const float*)d_in[0];
    const float* adj = (const float*)d_in[1];
    const float* W1  = (const float*)d_in[2];
    const float* W2  = (const float*)d_in[3];
    float* out = (float*)d_out;

    char* wsp = (char*)d_ws;
    unsigned*  nbr = (unsigned*) (wsp + 0);
    _Float16*  g16 = (_Float16*) (wsp + 196608);
    float*     ph  = (float*)    (wsp + 262144);

    build_gemms<<<NN, 512, 0, stream>>>(adj, z, W1, nbr, g16, out);
    hidk<<<dim3(3, NN), 1024, 0, stream>>>(nbr, g16, W2, ph);
    supp<<<NN, 512, 0, stream>>>(nbr, ph, out);
}

// Round 17
// 47.985 us; speedup vs baseline: 3.3290x; 1.7708x over previous
//
#include <hip/hip_runtime.h>
#include <hip/hip_bf16.h>

#define NN 512
#define NH 64
#define MAXD 96            // list capacity (deg mean 32, sigma 5.5 -> +11 sigma)
#define ZBYTE (511 * 128)  // sentinel -> byte row offset of row 511 (always zeroed)

typedef _Float16 h4 __attribute__((ext_vector_type(4)));

// ---------------- ws layout (bytes) ----------------
// nbr   : NN*MAXD*4 = 196608 @ 0       entries = r*128 (byte row offset), sentinel ZBYTE
// g16   : NN*NH*2   = 65536  @ 196608  fp16 z@W1 tile (unscaled)
// pcntC : NN*NN     = 262144 @ 262144  u8 pcntC[c][t] = #{r in nbr(c): r < t}
//                                      coalesced row write by block c; consumers do a
//                                      one-time strided byte gather pcntC[c*NN + i]
// ph    : NN*NN*4   = 1048576@ 524288  f32 ph[i][k] = deg_k*hid[i][k], valid k<i
// total = 1572864

// K1: 512 blocks x 512 thr. Every block builds the neighbor list + its own
// contiguous pcntC row for column c = b (adj symmetric -> coalesced row read;
// ballot compaction preserves sorted order). Blocks 0..255 also compute a
// 32x32 tile of out = z@z^T; blocks 256..271 a 32-row slab of g16.
__global__ __launch_bounds__(512) void build_gemms(const float* __restrict__ adj,
                                                   const float* __restrict__ z,
                                                   const float* __restrict__ W1,
                                                   unsigned* __restrict__ nbr,
                                                   unsigned char* __restrict__ pcntC,
                                                   _Float16* __restrict__ g16,
                                                   float* __restrict__ out) {
    __shared__ float As[32][34];
    __shared__ float Bs[32][34];
    __shared__ int wcnt[8];
    const int b = (int)blockIdx.x;
    const int tid = (int)threadIdx.x;
    const int lane = tid & 63, w = tid >> 6;

    {   // build list + pcntC row for column c = b
        const int c = b;
        bool f = (adj[c * NN + tid] != 0.0f);
        unsigned long long m = __ballot(f);
        int before = __popcll(m & ((1ull << lane) - 1ull));
        if (lane == 0) wcnt[w] = __popcll(m);
        __syncthreads();
        int pre = 0, total = 0;
        #pragma unroll
        for (int j = 0; j < 8; ++j) {
            int x = wcnt[j];
            pre += (j < w) ? x : 0;
            total += x;
        }
        pcntC[c * NN + tid] = (unsigned char)(pre + before);  // coalesced row write
        unsigned* row = nbr + c * MAXD;
        int pos = pre + before;
        if (f && pos < MAXD) row[pos] = (unsigned)(tid << 7);
        int m2 = total < MAXD ? total : MAXD;
        for (int j = m2 + tid; j < MAXD; j += 512) row[j] = ZBYTE;
        __syncthreads();
    }

    const int tx = tid & 15, py = tid >> 4;   // 16 x 32 thread layout
    if (b < 256) {
        // out = z @ z^T, 32x32 tile (bi, bj); 2 outputs/thread
        const int bi = b >> 4, bj = b & 15;
        float acc0 = 0.f, acc1 = 0.f;
        for (int kk = 0; kk < 256; kk += 32) {
            #pragma unroll
            for (int l = 0; l < 2; ++l) {
                int id = tid + (l << 9);
                int m = id >> 5, k = id & 31;
                As[k][m] = z[(bi * 32 + m) * 256 + kk + k];
                Bs[k][m] = z[(bj * 32 + m) * 256 + kk + k];
            }
            __syncthreads();
            #pragma unroll
            for (int k = 0; k < 32; ++k) {
                float a = As[k][py];
                float2 bb = *(const float2*)&Bs[k][tx * 2];
                acc0 = fmaf(a, bb.x, acc0);
                acc1 = fmaf(a, bb.y, acc1);
            }
            __syncthreads();
        }
        *(float2*)&out[(bi * 32 + py) * NN + bj * 32 + tx * 2] = make_float2(acc0, acc1);
    } else if (b < 272) {
        // g16 = fp16(z @ W1[:256]), 32-row slab; 4 outputs/thread
        const int bi = b - 256;
        float (*As2)[34] = As;
        float (*Bs2)[68] = (float(*)[68])&Bs[0][0];   // 16*68 = 1088 floats == Bs
        float a0 = 0.f, a1 = 0.f, a2 = 0.f, a3 = 0.f;
        for (int kk = 0; kk < 256; kk += 16) {
            {
                int m = tid >> 4, k = tid & 15;       // 32 x 16
                As2[k][m] = z[(bi * 32 + m) * 256 + kk + k];
            }
            #pragma unroll
            for (int l = 0; l < 2; ++l) {
                int id = tid + (l << 9);
                int k = id >> 6, n2 = id & 63;        // 16 x 64
                Bs2[k][n2] = W1[(kk + k) * 64 + n2];
            }
            __syncthreads();
            #pragma unroll
            for (int k = 0; k < 16; ++k) {
                float a = As2[k][py];
                float4 bb = *(const float4*)&Bs2[k][tx * 4];
                a0 = fmaf(a, bb.x, a0);
                a1 = fmaf(a, bb.y, a1);
                a2 = fmaf(a, bb.z, a2);
                a3 = fmaf(a, bb.w, a3);
            }
            __syncthreads();
        }
        h4 v = {(_Float16)a0, (_Float16)a1, (_Float16)a2, (_Float16)a3};
        *(h4*)&g16[(bi * 32 + py) * NH + tx * 4] = v;
    }
}

// K2: visit-balanced hid (R10 structure, measured 5.9us). Grid (3, 512):
// block (c, b) handles i = 511-b, k in [c*i/3, (c+1)*i/3). deg via ONE
// strided byte gather pcntC[tid*NN + i] per block (512 lines, L2-hot).
// g2[l][h] = deg_i[l]*g16[l][h], rows >= i zeroed. Quarter q of each wave
// owns one k; 2-deep rolling list prefetch. Stores ph = deg_k*hid.
__global__ __launch_bounds__(1024, 8) void hidk(const unsigned* __restrict__ nbr,
                                                const unsigned char* __restrict__ pcntC,
                                                const _Float16* __restrict__ g16,
                                                const float* __restrict__ W2,
                                                float* __restrict__ ph) {
    __shared__ _Float16 g2[NN * NH];   // 64 KB deg-scaled tile
    __shared__ float degl[NN];
    __shared__ short pcl[NN];
    const int i = 511 - (int)blockIdx.y;   // big i first
    const int c = (int)blockIdx.x;
    const int kc0 = (c * i) / 3, kc1 = ((c + 1) * i) / 3;
    if (kc0 >= kc1) return;
    const int tid = threadIdx.x, lane = tid & 63, w = tid >> 6;

    if (tid < NN) {
        int pc = (int)pcntC[tid * NN + i];           // strided byte gather (once)
        pcl[tid] = (short)pc;
        degl[tid] = (tid < i) ? rsqrtf((float)(pc > 0 ? pc : 1)) : 0.0f;
    }
    __syncthreads();
    {   // stage rows < i scaled; zero rows >= i (no global read for dead rows)
        const uint4* s = (const uint4*)g16;
        uint4* d = (uint4*)g2;
        const int ci = i << 3;             // live uint4 count
        for (int t = tid; t < ci; t += 1024) {
            int l = t >> 3;
            uint4 raw = s[t];
            _Float16 dh = (_Float16)degl[l];
            h4 dv = {dh, dh, dh, dh};
            h4 a0 = ((h4*)&raw)[0] * dv;
            h4 a1 = ((h4*)&raw)[1] * dv;
            uint4 o;
            ((h4*)&o)[0] = a0; ((h4*)&o)[1] = a1;
            d[t] = o;
        }
        const uint4 zz = {0u, 0u, 0u, 0u};
        for (int t = ci + tid; t < NN * 8; t += 1024) d[t] = zz;
    }
    __syncthreads();

    const int q = lane >> 4;                 // quarter 0..3
    const int lofs = (lane & 15) << 3;       // byte offset within 128B row
    const float4 w2v = *(const float4*)&W2[(lane & 15) << 2];
    const char* g2b = (const char*)g2;

    for (int k0 = kc0 + (w << 2); k0 < kc1; k0 += 64) {
        const int kq = k0 + q;
        const int kqc = kq < 511 ? kq : 511;
        int pk = (kq < kc1) ? (int)pcl[kqc] : 0;
        int mx = max(pk, __shfl_xor(pk, 16, 64));
        mx = max(mx, __shfl_xor(mx, 32, 64));
        const int nbu = __builtin_amdgcn_readfirstlane((mx + 3) >> 2);
        const uint4* l4 = (const uint4*)(nbr + kqc * MAXD);
        h4 acc0 = {}, acc1 = {};
        uint4 e0 = l4[0], e1 = l4[1];        // 2-deep rolling prefetch
        for (int g = 0; g < nbu; ++g) {
            uint4 en = l4[g + 2];            // harmless in-row over-read
            acc0 += *(const h4*)(g2b + (e0.x + lofs));
            acc1 += *(const h4*)(g2b + (e0.y + lofs));
            acc0 += *(const h4*)(g2b + (e0.z + lofs));
            acc1 += *(const h4*)(g2b + (e0.w + lofs));
            e0 = e1; e1 = en;
        }
        h4 acc = acc0 + acc1;
        const float dk = degl[kqc];
        float val = fmaxf(dk * (float)acc[0], 0.f) * w2v.x
                  + fmaxf(dk * (float)acc[1], 0.f) * w2v.y
                  + fmaxf(dk * (float)acc[2], 0.f) * w2v.z
                  + fmaxf(dk * (float)acc[3], 0.f) * w2v.w;
        #pragma unroll
        for (int mm = 1; mm <= 8; mm <<= 1) val += __shfl_xor(val, mm, 64);
        if ((lane & 15) == 0 && kq < kc1) ph[i * NN + kq] = dk * val;  // deg_k*hid
    }
}

// K3: supplement scatter (R10 structure, measured 2.4us). s[i][j] =
// 0.5*deg_j*sum_{k in nbr(j), k<i} ph[i][k]; out[i][j] += s, out[j][i] += s
// (block i owns row i & col i -> race-free). Over-reads hit phl[r>=i] == 0.
__global__ __launch_bounds__(512) void supp(const unsigned* __restrict__ nbr,
                                            const unsigned char* __restrict__ pcntC,
                                            const float* __restrict__ ph,
                                            float* __restrict__ out) {
    __shared__ float phl[NN];
    const int i = 511 - (int)blockIdx.x;
    if (i < 1) return;
    const int tid = threadIdx.x;
    const int pc = (int)pcntC[tid * NN + i];         // strided byte gather (once)
    phl[tid] = (tid < i) ? ph[i * NN + tid] : 0.0f;  // ph already deg_k-scaled
    __syncthreads();
    if (tid < i) {
        const float d = rsqrtf((float)(pc > 0 ? pc : 1));
        const uint4* l4 = (const uint4*)(nbr + tid * MAXD);
        const int nb = (pc + 3) >> 2;
        float s = 0.f;
        for (int g = 0; g < nb; ++g) {
            uint4 qv = l4[g];   // over-read entries land on phl[r>=i] == 0
            s += phl[qv.x >> 7] + phl[qv.y >> 7] + phl[qv.z >> 7] + phl[qv.w >> 7];
        }
        s *= 0.5f * d;
        out[i * NN + tid] += s;
        out[tid * NN + i] += s;
    }
}

extern "C" void kernel_launch(void* const* d_in, const int* in_sizes, int n_in,
                              void* d_out, int out_size, void* d_ws, size_t ws_size,
                              hipStream_t stream) {
    const float* z   = (const float*)d_in[0];
    const float* adj = (const float*)d_in[1];
    const float* W1  = (const float*)d_in[2];
    const float* W2  = (const float*)d_in[3];
    float* out = (float*)d_out;

    char* wsp = (char*)d_ws;
    unsigned*       nbr   = (unsigned*)      (wsp + 0);
    _Float16*       g16   = (_Float16*)      (wsp + 196608);
    unsigned char*  pcntC = (unsigned char*) (wsp + 262144);
    float*          ph    = (float*)         (wsp + 524288);

    build_gemms<<<NN, 512, 0, stream>>>(adj, z, W1, nbr, pcntC, g16, out);
    hidk<<<dim3(3, NN), 1024, 0, stream>>>(nbr, pcntC, g16, W2, ph);
    supp<<<NN, 512, 0, stream>>>(nbr, pcntC, ph, out);
}

// Round 18
// 45.656 us; speedup vs baseline: 3.4988x; 1.0510x over previous
//
#include <hip/hip_runtime.h>
#include <hip/hip_bf16.h>

#define NN 512
#define NH 64
#define MAXD 96            // list capacity (deg mean 32, sigma 5.5 -> +11 sigma)
#define ZBYTE (511 * 128)  // sentinel -> byte row offset of row 511 (always zeroed)

typedef _Float16 h4 __attribute__((ext_vector_type(4)));
typedef _Float16 h8 __attribute__((ext_vector_type(8)));
typedef float f32x4 __attribute__((ext_vector_type(4)));

// ---------------- ws layout (bytes) ----------------
// nbr   : NN*MAXD*4 = 196608 @ 0       entries = r*128 (byte row offset), sentinel ZBYTE
// g16   : NN*NH*2   = 65536  @ 196608  fp16 z@W1 tile (unscaled)
// pcntC : NN*NN     = 262144 @ 262144  u8 pcntC[c][t] = #{r in nbr(c): r < t}
// ph    : NN*NN*4   = 1048576@ 524288  f32 ph[i][k] = deg_k*hid[i][k], valid k<i
// total = 1572864

// K1: 512 blocks x 512 thr. Every block: build list + pcntC row for column
// c = b (adj symmetric). Blocks 0..255: one 32x32 tile of out = z@z^T via
// MFMA fp16 (f32 accum) — 4 waves x 8 mfma_f32_16x16x32_f16, z-rows staged
// fp16 in LDS (row pad +8 halves kills the 512B-stride bank conflict).
// Blocks 256..271: 32-row slab of g16 = fp16(z @ W1[:256]) (fp32 VALU).
__global__ __launch_bounds__(512) void build_gemms(const float* __restrict__ adj,
                                                   const float* __restrict__ z,
                                                   const float* __restrict__ W1,
                                                   unsigned* __restrict__ nbr,
                                                   unsigned char* __restrict__ pcntC,
                                                   _Float16* __restrict__ g16,
                                                   float* __restrict__ out) {
    __shared__ __align__(16) char smem[34048];   // union across phases
    const int b = (int)blockIdx.x;
    const int tid = (int)threadIdx.x;
    const int lane = tid & 63, w = tid >> 6;

    {   // ---- phase A: build list + pcntC row for column c = b ----
        int* wcnt = (int*)smem;
        const int c = b;
        bool f = (adj[c * NN + tid] != 0.0f);
        unsigned long long m = __ballot(f);
        int before = __popcll(m & ((1ull << lane) - 1ull));
        if (lane == 0) wcnt[w] = __popcll(m);
        __syncthreads();
        int pre = 0, total = 0;
        #pragma unroll
        for (int j = 0; j < 8; ++j) {
            int x = wcnt[j];
            pre += (j < w) ? x : 0;
            total += x;
        }
        pcntC[c * NN + tid] = (unsigned char)(pre + before);  // coalesced row write
        unsigned* row = nbr + c * MAXD;
        int pos = pre + before;
        if (f && pos < MAXD) row[pos] = (unsigned)(tid << 7);
        int m2 = total < MAXD ? total : MAXD;
        for (int j = m2 + tid; j < MAXD; j += 512) row[j] = ZBYTE;
        __syncthreads();
    }

    if (b < 256) {
        // ---- zz^T 32x32 tile (bi, bj) via MFMA fp16 ----
        const int bi = b >> 4, bj = b & 15;
        _Float16 (*As16)[264] = (_Float16(*)[264])smem;            // 32 x 264 fp16
        _Float16 (*Bs16)[264] = (_Float16(*)[264])(smem + 16896);  // 32 x 264 fp16
        #pragma unroll
        for (int l = 0; l < 4; ++l) {
            int idx = tid + (l << 9);             // 0..2047
            int r = idx >> 6, c4 = (idx & 63) << 2;
            float4 a  = *(const float4*)&z[(bi * 32 + r) * 256 + c4];
            float4 bb = *(const float4*)&z[(bj * 32 + r) * 256 + c4];
            h4 ah = {(_Float16)a.x,  (_Float16)a.y,  (_Float16)a.z,  (_Float16)a.w};
            h4 bh = {(_Float16)bb.x, (_Float16)bb.y, (_Float16)bb.z, (_Float16)bb.w};
            *(h4*)&As16[r][c4] = ah;
            *(h4*)&Bs16[r][c4] = bh;
        }
        __syncthreads();
        if (tid < 256) {                          // waves 0..3, one 16x16 subtile each
            const int mi = w & 1, ni = w >> 1;
            const int r16 = lane & 15, kg = (lane >> 4) << 3;
            f32x4 acc = {};
            #pragma unroll
            for (int kk = 0; kk < 256; kk += 32) {
                h8 av = *(const h8*)&As16[mi * 16 + r16][kk + kg];
                h8 bv = *(const h8*)&Bs16[ni * 16 + r16][kk + kg];
                acc = __builtin_amdgcn_mfma_f32_16x16x32_f16(av, bv, acc, 0, 0, 0);
            }
            // C/D layout: col = lane&15, row = (lane>>4)*4 + reg
            const int orow = bi * 32 + mi * 16 + ((lane >> 4) << 2);
            const int ocol = bj * 32 + ni * 16 + (lane & 15);
            #pragma unroll
            for (int j = 0; j < 4; ++j)
                out[(orow + j) * NN + ocol] = acc[j];
        }
    } else if (b < 272) {
        // ---- g16 = fp16(z @ W1[:256]), 32-row slab; 4 outputs/thread ----
        const int bi = b - 256;
        float (*As2)[34] = (float(*)[34])smem;             // 16 x 34 f32
        float (*Bs2)[68] = (float(*)[68])(smem + 2176);    // 16 x 68 f32
        const int tx = tid & 15, py = tid >> 4;
        float a0 = 0.f, a1 = 0.f, a2 = 0.f, a3 = 0.f;
        for (int kk = 0; kk < 256; kk += 16) {
            {
                int m = tid >> 4, k = tid & 15;            // 32 x 16
                As2[k][m] = z[(bi * 32 + m) * 256 + kk + k];
            }
            #pragma unroll
            for (int l = 0; l < 2; ++l) {
                int id = tid + (l << 9);
                int k = id >> 6, n2 = id & 63;             // 16 x 64
                Bs2[k][n2] = W1[(kk + k) * 64 + n2];
            }
            __syncthreads();
            #pragma unroll
            for (int k = 0; k < 16; ++k) {
                float a = As2[k][py];
                float4 bb = *(const float4*)&Bs2[k][tx * 4];
                a0 = fmaf(a, bb.x, a0);
                a1 = fmaf(a, bb.y, a1);
                a2 = fmaf(a, bb.z, a2);
                a3 = fmaf(a, bb.w, a3);
            }
            __syncthreads();
        }
        h4 v = {(_Float16)a0, (_Float16)a1, (_Float16)a2, (_Float16)a3};
        *(h4*)&g16[(bi * 32 + py) * NH + tx * 4] = v;
    }
}

// K2: visit-balanced hid (measured 5.9us). Grid (3, 512): block (c, b)
// handles i = 511-b, k in [c*i/3, (c+1)*i/3). deg via one strided byte
// gather pcntC[tid*NN + i]. g2[l][h] = deg_i[l]*g16[l][h], rows >= i zeroed.
// Quarter q of each wave owns one k; 2-deep rolling list prefetch.
__global__ __launch_bounds__(1024, 8) void hidk(const unsigned* __restrict__ nbr,
                                                const unsigned char* __restrict__ pcntC,
                                                const _Float16* __restrict__ g16,
                                                const float* __restrict__ W2,
                                                float* __restrict__ ph) {
    __shared__ _Float16 g2[NN * NH];   // 64 KB deg-scaled tile
    __shared__ float degl[NN];
    __shared__ short pcl[NN];
    const int i = 511 - (int)blockIdx.y;   // big i first
    const int c = (int)blockIdx.x;
    const int kc0 = (c * i) / 3, kc1 = ((c + 1) * i) / 3;
    if (kc0 >= kc1) return;
    const int tid = threadIdx.x, lane = tid & 63, w = tid >> 6;

    if (tid < NN) {
        int pc = (int)pcntC[tid * NN + i];           // strided byte gather (once)
        pcl[tid] = (short)pc;
        degl[tid] = (tid < i) ? rsqrtf((float)(pc > 0 ? pc : 1)) : 0.0f;
    }
    __syncthreads();
    {   // stage rows < i scaled; zero rows >= i
        const uint4* s = (const uint4*)g16;
        uint4* d = (uint4*)g2;
        const int ci = i << 3;
        for (int t = tid; t < ci; t += 1024) {
            int l = t >> 3;
            uint4 raw = s[t];
            _Float16 dh = (_Float16)degl[l];
            h4 dv = {dh, dh, dh, dh};
            h4 a0 = ((h4*)&raw)[0] * dv;
            h4 a1 = ((h4*)&raw)[1] * dv;
            uint4 o;
            ((h4*)&o)[0] = a0; ((h4*)&o)[1] = a1;
            d[t] = o;
        }
        const uint4 zz = {0u, 0u, 0u, 0u};
        for (int t = ci + tid; t < NN * 8; t += 1024) d[t] = zz;
    }
    __syncthreads();

    const int q = lane >> 4;
    const int lofs = (lane & 15) << 3;
    const float4 w2v = *(const float4*)&W2[(lane & 15) << 2];
    const char* g2b = (const char*)g2;

    for (int k0 = kc0 + (w << 2); k0 < kc1; k0 += 64) {
        const int kq = k0 + q;
        const int kqc = kq < 511 ? kq : 511;
        int pk = (kq < kc1) ? (int)pcl[kqc] : 0;
        int mx = max(pk, __shfl_xor(pk, 16, 64));
        mx = max(mx, __shfl_xor(mx, 32, 64));
        const int nbu = __builtin_amdgcn_readfirstlane((mx + 3) >> 2);
        const uint4* l4 = (const uint4*)(nbr + kqc * MAXD);
        h4 acc0 = {}, acc1 = {};
        uint4 e0 = l4[0], e1 = l4[1];        // 2-deep rolling prefetch
        for (int g = 0; g < nbu; ++g) {
            uint4 en = l4[g + 2];            // harmless in-row over-read
            acc0 += *(const h4*)(g2b + (e0.x + lofs));
            acc1 += *(const h4*)(g2b + (e0.y + lofs));
            acc0 += *(const h4*)(g2b + (e0.z + lofs));
            acc1 += *(const h4*)(g2b + (e0.w + lofs));
            e0 = e1; e1 = en;
        }
        h4 acc = acc0 + acc1;
        const float dk = degl[kqc];
        float val = fmaxf(dk * (float)acc[0], 0.f) * w2v.x
                  + fmaxf(dk * (float)acc[1], 0.f) * w2v.y
                  + fmaxf(dk * (float)acc[2], 0.f) * w2v.z
                  + fmaxf(dk * (float)acc[3], 0.f) * w2v.w;
        #pragma unroll
        for (int mm = 1; mm <= 8; mm <<= 1) val += __shfl_xor(val, mm, 64);
        if ((lane & 15) == 0 && kq < kc1) ph[i * NN + kq] = dk * val;  // deg_k*hid
    }
}

// K3: supplement scatter (measured 2.4us). s[i][j] = 0.5*deg_j*
// sum_{k in nbr(j), k<i} ph[i][k]; out[i][j] += s, out[j][i] += s
// (block i owns row i & col i -> race-free). Over-reads hit phl[r>=i] == 0.
__global__ __launch_bounds__(512) void supp(const unsigned* __restrict__ nbr,
                                            const unsigned char* __restrict__ pcntC,
                                            const float* __restrict__ ph,
                                            float* __restrict__ out) {
    __shared__ float phl[NN];
    const int i = 511 - (int)blockIdx.x;
    if (i < 1) return;
    const int tid = threadIdx.x;
    const int pc = (int)pcntC[tid * NN + i];         // strided byte gather (once)
    phl[tid] = (tid < i) ? ph[i * NN + tid] : 0.0f;  // ph already deg_k-scaled
    __syncthreads();
    if (tid < i) {
        const float d = rsqrtf((float)(pc > 0 ? pc : 1));
        const uint4* l4 = (const uint4*)(nbr + tid * MAXD);
        const int nb = (pc + 3) >> 2;
        float s = 0.f;
        for (int g = 0; g < nb; ++g) {
            uint4 qv = l4[g];   // over-read entries land on phl[r>=i] == 0
            s += phl[qv.x >> 7] + phl[qv.y >> 7] + phl[qv.z >> 7] + phl[qv.w >> 7];
        }
        s *= 0.5f * d;
        out[i * NN + tid] += s;
        out[tid * NN + i] += s;
    }
}

extern "C" void kernel_launch(void* const* d_in, const int* in_sizes, int n_in,
                              void* d_out, int out_size, void* d_ws, size_t ws_size,
                              hipStream_t stream) {
    const float* z   = (const float*)d_in[0];
    const float* adj = (const float*)d_in[1];
    const float* W1  = (const float*)d_in[2];
    const float* W2  = (const float*)d_in[3];
    float* out = (float*)d_out;

    char* wsp = (char*)d_ws;
    unsigned*       nbr   = (unsigned*)      (wsp + 0);
    _Float16*       g16   = (_Float16*)      (wsp + 196608);
    unsigned char*  pcntC = (unsigned char*) (wsp + 262144);
    float*          ph    = (float*)         (wsp + 524288);

    build_gemms<<<NN, 512, 0, stream>>>(adj, z, W1, nbr, pcntC, g16, out);
    hidk<<<dim3(3, NN), 1024, 0, stream>>>(nbr, pcntC, g16, W2, ph);
    supp<<<NN, 512, 0, stream>>>(nbr, pcntC, ph, out);
}

// Round 19
// 36.717 us; speedup vs baseline: 4.3506x; 1.2435x over previous
//
#include <hip/hip_runtime.h>
#include <hip/hip_bf16.h>

#define NN 512
#define NH 64
#define MAXD 96            // list capacity (deg mean 32, sigma 5.5 -> +11 sigma)
#define ZBYTE (511 * 128)  // sentinel -> byte row offset of row 511 (always zeroed)

typedef _Float16 h4 __attribute__((ext_vector_type(4)));
typedef _Float16 h8 __attribute__((ext_vector_type(8)));
typedef float f32x4 __attribute__((ext_vector_type(4)));

// ---------------- ws layout (bytes) ----------------
// nbr   : NN*MAXD*4 = 196608 @ 0       entries = r*128 (byte row offset), sentinel ZBYTE
// g16   : NN*NH*2   = 65536  @ 196608  fp16 z@W1 tile (unscaled)
// pcntC : NN*NN     = 262144 @ 262144  u8 pcntC[c][t] = #{r in nbr(c): r < t}
// ph    : NN*NN*4   = 1048576@ 524288  f32 ph[i][k] = deg_k*hid[i][k], valid k<i
// total = 1572864

// K1: 512 blocks x 512 thr. Every block: build list + pcntC row for column
// c = b (adj symmetric). Blocks 0..255: one 32x32 tile of out = z@z^T via
// MFMA fp16 (verified layout, R18). Blocks 256..287: one 16-row slab of
// g16 = fp16(z @ W1[:256]) via MFMA (W1 staged transposed fp16 in LDS).
__global__ __launch_bounds__(512) void build_gemms(const float* __restrict__ adj,
                                                   const float* __restrict__ z,
                                                   const float* __restrict__ W1,
                                                   unsigned* __restrict__ nbr,
                                                   unsigned char* __restrict__ pcntC,
                                                   _Float16* __restrict__ g16,
                                                   float* __restrict__ out) {
    __shared__ __align__(16) char smem[42240];   // union across phases
    const int b = (int)blockIdx.x;
    const int tid = (int)threadIdx.x;
    const int lane = tid & 63, w = tid >> 6;

    {   // ---- phase A: build list + pcntC row for column c = b ----
        int* wcnt = (int*)smem;
        const int c = b;
        bool f = (adj[c * NN + tid] != 0.0f);
        unsigned long long m = __ballot(f);
        int before = __popcll(m & ((1ull << lane) - 1ull));
        if (lane == 0) wcnt[w] = __popcll(m);
        __syncthreads();
        int pre = 0, total = 0;
        #pragma unroll
        for (int j = 0; j < 8; ++j) {
            int x = wcnt[j];
            pre += (j < w) ? x : 0;
            total += x;
        }
        pcntC[c * NN + tid] = (unsigned char)(pre + before);  // coalesced row write
        unsigned* row = nbr + c * MAXD;
        int pos = pre + before;
        if (f && pos < MAXD) row[pos] = (unsigned)(tid << 7);
        int m2 = total < MAXD ? total : MAXD;
        for (int j = m2 + tid; j < MAXD; j += 512) row[j] = ZBYTE;
        __syncthreads();
    }

    if (b < 256) {
        // ---- zz^T 32x32 tile (bi, bj) via MFMA fp16 ----
        const int bi = b >> 4, bj = b & 15;
        _Float16 (*As16)[264] = (_Float16(*)[264])smem;            // 32 x 264 fp16
        _Float16 (*Bs16)[264] = (_Float16(*)[264])(smem + 16896);  // 32 x 264 fp16
        #pragma unroll
        for (int l = 0; l < 4; ++l) {
            int idx = tid + (l << 9);             // 0..2047
            int r = idx >> 6, c4 = (idx & 63) << 2;
            float4 a  = *(const float4*)&z[(bi * 32 + r) * 256 + c4];
            float4 bb = *(const float4*)&z[(bj * 32 + r) * 256 + c4];
            h4 ah = {(_Float16)a.x,  (_Float16)a.y,  (_Float16)a.z,  (_Float16)a.w};
            h4 bh = {(_Float16)bb.x, (_Float16)bb.y, (_Float16)bb.z, (_Float16)bb.w};
            *(h4*)&As16[r][c4] = ah;
            *(h4*)&Bs16[r][c4] = bh;
        }
        __syncthreads();
        if (tid < 256) {                          // waves 0..3, one 16x16 subtile each
            const int mi = w & 1, ni = w >> 1;
            const int r16 = lane & 15, kg = (lane >> 4) << 3;
            f32x4 acc = {};
            #pragma unroll
            for (int kk = 0; kk < 256; kk += 32) {
                h8 av = *(const h8*)&As16[mi * 16 + r16][kk + kg];
                h8 bv = *(const h8*)&Bs16[ni * 16 + r16][kk + kg];
                acc = __builtin_amdgcn_mfma_f32_16x16x32_f16(av, bv, acc, 0, 0, 0);
            }
            // C/D layout: col = lane&15, row = (lane>>4)*4 + reg  (HW-verified R18)
            const int orow = bi * 32 + mi * 16 + ((lane >> 4) << 2);
            const int ocol = bj * 32 + ni * 16 + (lane & 15);
            #pragma unroll
            for (int j = 0; j < 4; ++j)
                out[(orow + j) * NN + ocol] = acc[j];
        }
    } else if (b < 288) {
        // ---- g16 = fp16(z @ W1[:256]) via MFMA, 16-row slab ----
        const int bi = b - 256;                    // slab of rows [16*bi, 16*bi+16)
        _Float16 (*BsT)[264] = (_Float16(*)[264])smem;             // 64 x 264 (W1^T)
        _Float16 (*Asg)[264] = (_Float16(*)[264])(smem + 33792);   // 16 x 264 (z rows)
        #pragma unroll
        for (int it = 0; it < 8; ++it) {           // stage W1^T: 256x16 float4 reads
            int idx = tid + (it << 9);             // 0..4095
            int k = idx >> 4, n4 = (idx & 15) << 2;
            float4 wv = *(const float4*)&W1[k * 64 + n4];
            BsT[n4 + 0][k] = (_Float16)wv.x;
            BsT[n4 + 1][k] = (_Float16)wv.y;
            BsT[n4 + 2][k] = (_Float16)wv.z;
            BsT[n4 + 3][k] = (_Float16)wv.w;
        }
        #pragma unroll
        for (int it = 0; it < 2; ++it) {           // stage 16 z rows
            int idx = tid + (it << 9);             // 0..1023
            int r = idx >> 6, c4 = (idx & 63) << 2;
            float4 a = *(const float4*)&z[(bi * 16 + r) * 256 + c4];
            h4 ah = {(_Float16)a.x, (_Float16)a.y, (_Float16)a.z, (_Float16)a.w};
            *(h4*)&Asg[r][c4] = ah;
        }
        __syncthreads();
        if (tid < 256) {                           // wave w: col-tile n16 = 16*w
            const int n16 = w << 4;
            const int r16 = lane & 15, kg = (lane >> 4) << 3;
            f32x4 acc = {};
            #pragma unroll
            for (int kk = 0; kk < 256; kk += 32) {
                h8 av = *(const h8*)&Asg[r16][kk + kg];
                h8 bv = *(const h8*)&BsT[n16 + r16][kk + kg];
                acc = __builtin_amdgcn_mfma_f32_16x16x32_f16(av, bv, acc, 0, 0, 0);
            }
            const int orow = bi * 16 + ((lane >> 4) << 2);
            const int ocol = n16 + (lane & 15);
            #pragma unroll
            for (int j = 0; j < 4; ++j)
                g16[(orow + j) * NH + ocol] = (_Float16)acc[j];
        }
    }
}

// K2: visit-balanced hid (measured 5.9us). Grid (3, 512): block (c, b)
// handles i = 511-b, k in [c*i/3, (c+1)*i/3). deg via one strided byte
// gather pcntC[tid*NN + i]. g2[l][h] = deg_i[l]*g16[l][h], rows >= i zeroed.
// Quarter q of each wave owns one k; 2-deep rolling list prefetch.
__global__ __launch_bounds__(1024, 8) void hidk(const unsigned* __restrict__ nbr,
                                                const unsigned char* __restrict__ pcntC,
                                                const _Float16* __restrict__ g16,
                                                const float* __restrict__ W2,
                                                float* __restrict__ ph) {
    __shared__ _Float16 g2[NN * NH];   // 64 KB deg-scaled tile
    __shared__ float degl[NN];
    __shared__ short pcl[NN];
    const int i = 511 - (int)blockIdx.y;   // big i first
    const int c = (int)blockIdx.x;
    const int kc0 = (c * i) / 3, kc1 = ((c + 1) * i) / 3;
    if (kc0 >= kc1) return;
    const int tid = threadIdx.x, lane = tid & 63, w = tid >> 6;

    if (tid < NN) {
        int pc = (int)pcntC[tid * NN + i];           // strided byte gather (once)
        pcl[tid] = (short)pc;
        degl[tid] = (tid < i) ? rsqrtf((float)(pc > 0 ? pc : 1)) : 0.0f;
    }
    __syncthreads();
    {   // stage rows < i scaled; zero rows >= i
        const uint4* s = (const uint4*)g16;
        uint4* d = (uint4*)g2;
        const int ci = i << 3;
        for (int t = tid; t < ci; t += 1024) {
            int l = t >> 3;
            uint4 raw = s[t];
            _Float16 dh = (_Float16)degl[l];
            h4 dv = {dh, dh, dh, dh};
            h4 a0 = ((h4*)&raw)[0] * dv;
            h4 a1 = ((h4*)&raw)[1] * dv;
            uint4 o;
            ((h4*)&o)[0] = a0; ((h4*)&o)[1] = a1;
            d[t] = o;
        }
        const uint4 zz = {0u, 0u, 0u, 0u};
        for (int t = ci + tid; t < NN * 8; t += 1024) d[t] = zz;
    }
    __syncthreads();

    const int q = lane >> 4;
    const int lofs = (lane & 15) << 3;
    const float4 w2v = *(const float4*)&W2[(lane & 15) << 2];
    const char* g2b = (const char*)g2;

    for (int k0 = kc0 + (w << 2); k0 < kc1; k0 += 64) {
        const int kq = k0 + q;
        const int kqc = kq < 511 ? kq : 511;
        int pk = (kq < kc1) ? (int)pcl[kqc] : 0;
        int mx = max(pk, __shfl_xor(pk, 16, 64));
        mx = max(mx, __shfl_xor(mx, 32, 64));
        const int nbu = __builtin_amdgcn_readfirstlane((mx + 3) >> 2);
        const uint4* l4 = (const uint4*)(nbr + kqc * MAXD);
        h4 acc0 = {}, acc1 = {};
        uint4 e0 = l4[0], e1 = l4[1];        // 2-deep rolling prefetch
        for (int g = 0; g < nbu; ++g) {
            uint4 en = l4[g + 2];            // harmless in-row over-read
            acc0 += *(const h4*)(g2b + (e0.x + lofs));
            acc1 += *(const h4*)(g2b + (e0.y + lofs));
            acc0 += *(const h4*)(g2b + (e0.z + lofs));
            acc1 += *(const h4*)(g2b + (e0.w + lofs));
            e0 = e1; e1 = en;
        }
        h4 acc = acc0 + acc1;
        const float dk = degl[kqc];
        float val = fmaxf(dk * (float)acc[0], 0.f) * w2v.x
                  + fmaxf(dk * (float)acc[1], 0.f) * w2v.y
                  + fmaxf(dk * (float)acc[2], 0.f) * w2v.z
                  + fmaxf(dk * (float)acc[3], 0.f) * w2v.w;
        #pragma unroll
        for (int mm = 1; mm <= 8; mm <<= 1) val += __shfl_xor(val, mm, 64);
        if ((lane & 15) == 0 && kq < kc1) ph[i * NN + kq] = dk * val;  // deg_k*hid
    }
}

// K3: supplement scatter (measured 2.4us). s[i][j] = 0.5*deg_j*
// sum_{k in nbr(j), k<i} ph[i][k]; out[i][j] += s, out[j][i] += s
// (block i owns row i & col i -> race-free). Over-reads hit phl[r>=i] == 0.
__global__ __launch_bounds__(512) void supp(const unsigned* __restrict__ nbr,
                                            const unsigned char* __restrict__ pcntC,
                                            const float* __restrict__ ph,
                                            float* __restrict__ out) {
    __shared__ float phl[NN];
    const int i = 511 - (int)blockIdx.x;
    if (i < 1) return;
    const int tid = threadIdx.x;
    const int pc = (int)pcntC[tid * NN + i];         // strided byte gather (once)
    phl[tid] = (tid < i) ? ph[i * NN + tid] : 0.0f;  // ph already deg_k-scaled
    __syncthreads();
    if (tid < i) {
        const float d = rsqrtf((float)(pc > 0 ? pc : 1));
        const uint4* l4 = (const uint4*)(nbr + tid * MAXD);
        const int nb = (pc + 3) >> 2;
        float s = 0.f;
        for (int g = 0; g < nb; ++g) {
            uint4 qv = l4[g];   // over-read entries land on phl[r>=i] == 0
            s += phl[qv.x >> 7] + phl[qv.y >> 7] + phl[qv.z >> 7] + phl[qv.w >> 7];
        }
        s *= 0.5f * d;
        out[i * NN + tid] += s;
        out[tid * NN + i] += s;
    }
}

extern "C" void kernel_launch(void* const* d_in, const int* in_sizes, int n_in,
                              void* d_out, int out_size, void* d_ws, size_t ws_size,
                              hipStream_t stream) {
    const float* z   = (const float*)d_in[0];
    const float* adj = (const float*)d_in[1];
    const float* W1  = (const float*)d_in[2];
    const float* W2  = (const float*)d_in[3];
    float* out = (float*)d_out;

    char* wsp = (char*)d_ws;
    unsigned*       nbr   = (unsigned*)      (wsp + 0);
    _Float16*       g16   = (_Float16*)      (wsp + 196608);
    unsigned char*  pcntC = (unsigned char*) (wsp + 262144);
    float*          ph    = (float*)         (wsp + 524288);

    build_gemms<<<NN, 512, 0, stream>>>(adj, z, W1, nbr, pcntC, g16, out);
    hidk<<<dim3(3, NN), 1024, 0, stream>>>(nbr, pcntC, g16, W2, ph);
    supp<<<NN, 512, 0, stream>>>(nbr, pcntC, ph, out);
}